// Round 2
// baseline (416.432 us; speedup 1.0000x reference)
//
#include <hip/hip_runtime.h>
#include <hip/hip_bf16.h>

#define N_ROWS 65536
#define DIM    512
#define KCLS   512
#define BUCKET 256   // padded per-class bucket for counting sort (max cnt ~170)

typedef __bf16 bf16x8 __attribute__((ext_vector_type(8)));
typedef float  f32x16 __attribute__((ext_vector_type(16)));

__device__ __forceinline__ float bf2f(ushort u) {
    union { unsigned int i; float f; } v; v.i = ((unsigned int)u) << 16; return v.f;
}

// ---------- Kernel 1: normalize -> bf16 embb + histogram + bucket scatter --
__global__ __launch_bounds__(256) void rnorm_embb_kernel(
    const float* __restrict__ emb, const int* __restrict__ labels,
    ushort* __restrict__ embb, int* __restrict__ counts,
    ushort* __restrict__ order16)
{
    const int tid  = threadIdx.x;
    const int wave = tid >> 6;
    const int lane = tid & 63;
    const int row  = blockIdx.x * 4 + wave;

    const float4* ep = (const float4*)(emb + (size_t)row * DIM + lane * 8);
    const float4 e0 = ep[0], e1 = ep[1];
    float ss = e0.x*e0.x + e0.y*e0.y + e0.z*e0.z + e0.w*e0.w
             + e1.x*e1.x + e1.y*e1.y + e1.z*e1.z + e1.w*e1.w;
    #pragma unroll
    for (int off = 1; off < 64; off <<= 1)
        ss += __shfl_xor(ss, off, 64);
    const float rn = 1.0f / fmaxf(sqrtf(ss), 1e-12f);

    bf16x8 h;
    h[0] = (__bf16)(e0.x * rn); h[1] = (__bf16)(e0.y * rn);
    h[2] = (__bf16)(e0.z * rn); h[3] = (__bf16)(e0.w * rn);
    h[4] = (__bf16)(e1.x * rn); h[5] = (__bf16)(e1.y * rn);
    h[6] = (__bf16)(e1.z * rn); h[7] = (__bf16)(e1.w * rn);
    *(bf16x8*)(embb + (size_t)row * DIM + lane * 8) = h;

    if (lane == 0) {
        const int l   = labels[row];
        const int pos = atomicAdd(&counts[l], 1);
        order16[l * BUCKET + pos] = (ushort)row;
    }
}

// ---------- Kernel 2: per-class sums & bf16 centroids ----------------------
__global__ __launch_bounds__(256) void class_sum_kernel(
    const ushort* __restrict__ embb,
    const int* __restrict__ counts, const ushort* __restrict__ order16,
    float* __restrict__ sums, ushort* __restrict__ centb)
{
    __shared__ float part[4][DIM];

    const int cls  = blockIdx.x;
    const int tid  = threadIdx.x;
    const int wave = tid >> 6;
    const int lane = tid & 63;
    const int cnt  = counts[cls];
    const int base = cls * BUCKET;
    const int d8   = lane * 8;

    float a[8] = {};
    float b2[8] = {};
    int j = wave;
    for (; j + 4 < cnt; j += 8) {       // 2 independent gather chains in flight
        const int r1 = order16[base + j];
        const int r2 = order16[base + j + 4];
        const uint4 u1 = *(const uint4*)(embb + (size_t)r1 * DIM + d8);
        const uint4 u2 = *(const uint4*)(embb + (size_t)r2 * DIM + d8);
        const ushort* s1 = (const ushort*)&u1;
        const ushort* s2 = (const ushort*)&u2;
        #pragma unroll
        for (int q = 0; q < 8; ++q) { a[q] += bf2f(s1[q]); b2[q] += bf2f(s2[q]); }
    }
    if (j < cnt) {
        const int r = order16[base + j];
        const uint4 u = *(const uint4*)(embb + (size_t)r * DIM + d8);
        const ushort* s1 = (const ushort*)&u;
        #pragma unroll
        for (int q = 0; q < 8; ++q) a[q] += bf2f(s1[q]);
    }
    #pragma unroll
    for (int q = 0; q < 8; ++q) part[wave][d8 + q] = a[q] + b2[q];
    __syncthreads();

    const int d0 = tid * 2;
    const float s0 = part[0][d0]   + part[1][d0]   + part[2][d0]   + part[3][d0];
    const float s1 = part[0][d0+1] + part[1][d0+1] + part[2][d0+1] + part[3][d0+1];
    *(float2*)(sums + (size_t)cls * DIM + d0) = make_float2(s0, s1);
    const float cinv = 1.0f / fmaxf((float)cnt, 1.0f);
    const __bf16 c0 = (__bf16)(s0 * cinv);
    const __bf16 c1 = (__bf16)(s1 * cinv);
    ushort2 cpk;
    cpk.x = *(const ushort*)&c0;
    cpk.y = *(const ushort*)&c1;
    *(ushort2*)(centb + (size_t)cls * DIM + d0) = cpk;
}

// ---------- Kernel 3: MFMA GEMM + own + logsumexp + loss + finalize --------
// Zero-barrier K-loop: both A and B fragments are gathered straight from
// global (each 16B/lane frag load touches 32 rows x one full 64B line; A is
// L1-shared across the block's 4 waves, B is nontemporal streaming from L2).
// 256-thr blocks, BM=64, wave = 64 rows x 128 cols -> all 512 cols in one
// pass, single softmax. acc[2][4]=128 AGPR -> 2 blocks/CU, waves desynced.
#define BM 64

#define MFMA(d_, a_, b_) d_ = __builtin_amdgcn_mfma_f32_32x32x16_bf16(a_, b_, d_, 0, 0, 0)

__global__ __launch_bounds__(256, 2) void fused_loss_kernel(
    const ushort* __restrict__ embb, const int* __restrict__ labels,
    const int* __restrict__ counts, const float* __restrict__ sums,
    const ushort* __restrict__ centb,
    const float* __restrict__ wp, const float* __restrict__ bp,
    float* __restrict__ loss_acc, int* __restrict__ done,
    float* __restrict__ out)
{
    __shared__ float m_ws[4][BM];
    __shared__ float s_ws[4][BM];
    __shared__ float ll_s[BM];
    __shared__ float own_s[BM];
    __shared__ int   lbl_s[BM];
    __shared__ int   rep_s[BM];

    const int tid  = threadIdx.x;
    const int wid  = tid >> 6;       // 0..3
    const int lane = tid & 63;
    const int ln31 = lane & 31;
    const int half = lane >> 5;
    const int r0   = blockIdx.x * BM;

    // ---- Phase A: leave-one-out own logit per row ----
    for (int rr = wid; rr < BM; rr += 4) {
        const int row = r0 + rr;
        const int l   = labels[row];
        const uint4 ev = *(const uint4*)(embb + (size_t)row * DIM + lane * 8);
        const ushort* eu = (const ushort*)&ev;
        const float4* sp = (const float4*)(sums + (size_t)l * DIM + lane * 8);
        const float4 s0 = sp[0], s1 = sp[1];
        const float sv[8] = {s0.x, s0.y, s0.z, s0.w, s1.x, s1.y, s1.z, s1.w};
        float d1 = 0.f, d2 = 0.f;
        #pragma unroll
        for (int jj = 0; jj < 8; ++jj) {
            const float e  = bf2f(eu[jj]);
            const float df = sv[jj] - e;
            d1 += e * df;
            d2 += df * df;
        }
        #pragma unroll
        for (int off = 32; off > 0; off >>= 1) {
            d1 += __shfl_down(d1, off, 64);
            d2 += __shfl_down(d2, off, 64);
        }
        if (lane == 0) {
            own_s[rr] = d1 / fmaxf(sqrtf(d2), 1e-12f);
            lbl_s[rr] = l;
            rep_s[rr] = (counts[l] > 1) ? 1 : 0;
        }
    }
    __syncthreads();

    // ---- fragment base pointers (lane-mapped: ln31 -> row/col, half -> k) --
    const int cb = wid * 128;    // this wave's 128-col panel
    const ushort* aB0 = embb  + (size_t)(r0 + ln31) * DIM + half * 8;  // rows 0..31
    const ushort* aB1 = aB0 + (size_t)32 * DIM;                        // rows 32..63
    const ushort* bB0 = centb + (size_t)(cb + ln31) * DIM + half * 8;  // cols 0..31
    const ushort* bB1 = bB0 + (size_t)32 * DIM;
    const ushort* bB2 = bB0 + (size_t)64 * DIM;
    const ushort* bB3 = bB0 + (size_t)96 * DIM;

    const float wv = fmaxf(wp[0], 1e-6f);
    const float bv = bp[0];

    f32x16 acc[2][4] = {};   // [row-frag][col-frag] -- static indices only

    // ---- K-loop: 16 steps of 32, NO barriers, NO LDS ----
    #pragma unroll 2
    for (int t = 0; t < 16; ++t) {
        const int ko = t * 32;
        const bf16x8 a00 = *(const bf16x8*)(aB0 + ko);        // ks=0
        const bf16x8 a10 = *(const bf16x8*)(aB1 + ko);
        const bf16x8 a01 = *(const bf16x8*)(aB0 + ko + 16);   // ks=1
        const bf16x8 a11 = *(const bf16x8*)(aB1 + ko + 16);
        const bf16x8 b00 = __builtin_nontemporal_load((const bf16x8*)(bB0 + ko));
        const bf16x8 b10 = __builtin_nontemporal_load((const bf16x8*)(bB1 + ko));
        const bf16x8 b20 = __builtin_nontemporal_load((const bf16x8*)(bB2 + ko));
        const bf16x8 b30 = __builtin_nontemporal_load((const bf16x8*)(bB3 + ko));
        const bf16x8 b01 = __builtin_nontemporal_load((const bf16x8*)(bB0 + ko + 16));
        const bf16x8 b11 = __builtin_nontemporal_load((const bf16x8*)(bB1 + ko + 16));
        const bf16x8 b21 = __builtin_nontemporal_load((const bf16x8*)(bB2 + ko + 16));
        const bf16x8 b31 = __builtin_nontemporal_load((const bf16x8*)(bB3 + ko + 16));

        MFMA(acc[0][0], a00, b00); MFMA(acc[1][0], a10, b00);
        MFMA(acc[0][1], a00, b10); MFMA(acc[1][1], a10, b10);
        MFMA(acc[0][2], a00, b20); MFMA(acc[1][2], a10, b20);
        MFMA(acc[0][3], a00, b30); MFMA(acc[1][3], a10, b30);
        MFMA(acc[0][0], a01, b01); MFMA(acc[1][0], a11, b01);
        MFMA(acc[0][1], a01, b11); MFMA(acc[1][1], a11, b11);
        MFMA(acc[0][2], a01, b21); MFMA(acc[1][2], a11, b21);
        MFMA(acc[0][3], a01, b31); MFMA(acc[1][3], a11, b31);
    }

    // ---- epilogue: per-wave row max / sum-exp over its 128 cols ----
    #pragma unroll
    for (int mt = 0; mt < 2; ++mt) {
        #pragma unroll
        for (int reg = 0; reg < 16; ++reg) {
            const int row = mt * 32 + (reg & 3) + 8 * (reg >> 2) + 4 * half;
            const int lbl = lbl_s[row];
            float v0 = wv * acc[mt][0][reg] + bv;
            float v1 = wv * acc[mt][1][reg] + bv;
            float v2 = wv * acc[mt][2][reg] + bv;
            float v3 = wv * acc[mt][3][reg] + bv;
            const int c = cb + ln31;
            if (c == lbl)      { if (rep_s[row]) v0 = wv * own_s[row] + bv; ll_s[row] = v0; }
            if (c + 32 == lbl) { if (rep_s[row]) v1 = wv * own_s[row] + bv; ll_s[row] = v1; }
            if (c + 64 == lbl) { if (rep_s[row]) v2 = wv * own_s[row] + bv; ll_s[row] = v2; }
            if (c + 96 == lbl) { if (rep_s[row]) v3 = wv * own_s[row] + bv; ll_s[row] = v3; }
            float mx = fmaxf(fmaxf(v0, v1), fmaxf(v2, v3));
            #pragma unroll
            for (int off = 1; off < 32; off <<= 1)
                mx = fmaxf(mx, __shfl_xor(mx, off, 64));
            float s = __expf(v0 - mx) + __expf(v1 - mx)
                    + __expf(v2 - mx) + __expf(v3 - mx);
            #pragma unroll
            for (int off = 1; off < 32; off <<= 1)
                s += __shfl_xor(s, off, 64);
            if (ln31 == 0) { m_ws[wid][row] = mx; s_ws[wid][row] = s; }
        }
    }
    __syncthreads();

    // ---- final merge over 4 col-waves + loss reduction (single wave) ----
    if (tid < 64) {
        const int rr = tid;
        float m = m_ws[0][rr];
        #pragma unroll
        for (int w = 1; w < 4; ++w) m = fmaxf(m, m_ws[w][rr]);
        float s = 0.f;
        #pragma unroll
        for (int w = 0; w < 4; ++w) s += s_ws[w][rr] * __expf(m_ws[w][rr] - m);
        float loss = m + __logf(s) - ll_s[rr];
        #pragma unroll
        for (int off = 32; off > 0; off >>= 1)
            loss += __shfl_down(loss, off, 64);
        if (tid == 0) {
            atomicAdd(loss_acc, loss);
            __threadfence();
            const int t = atomicAdd(done, 1);
            if (t == (N_ROWS / BM) - 1) {
                const float tot = atomicAdd(loss_acc, 0.0f);  // coherent read
                out[0] = tot / (float)N_ROWS;
            }
        }
    }
}

extern "C" void kernel_launch(void* const* d_in, const int* in_sizes, int n_in,
                              void* d_out, int out_size, void* d_ws, size_t ws_size,
                              hipStream_t stream)
{
    const float* emb    = (const float*)d_in[0];
    const int*   labels = (const int*)d_in[1];
    const float* wp     = (const float*)d_in[2];
    const float* bp     = (const float*)d_in[3];
    float* out = (float*)d_out;

    char* ws = (char*)d_ws;
    ushort* embb    = (ushort*)(ws + 0);              // 64 MiB
    ushort* order16 = (ushort*)(ws + 67108864);       // 512*256*2 = 256 KiB
    float*  sums    = (float*) (ws + 67371008);       // 1 MiB
    ushort* centb   = (ushort*)(ws + 68419584);       // 512 KiB
    int*    counts  = (int*)   (ws + 68943872);       // 2048 B
    float*  loss_acc= (float*) (ws + 68945920);       // 4 B
    int*    done    = (int*)   (ws + 68945924);       // 4 B

    // zero counts + loss_acc + done in one memset (contiguous 2056 B)
    hipMemsetAsync(counts, 0, 2056, stream);

    rnorm_embb_kernel<<<N_ROWS / 4, 256, 0, stream>>>(emb, labels, embb, counts, order16);
    class_sum_kernel<<<KCLS, 256, 0, stream>>>(embb, counts, order16, sums, centb);
    fused_loss_kernel<<<N_ROWS / BM, 256, 0, stream>>>(embb, labels, counts, sums,
                                                       centb, wp, bp, loss_acc, done, out);
}